// Round 5
// baseline (318.462 us; speedup 1.0000x reference)
//
#include <hip/hip_runtime.h>
#include <math.h>

#define Bn 8
#define Nn 262144
#define Kk 256
#define Dd 16
#define MCAP 4096
#define MSEL 1024
#define CHUNK 1024
#define NCH (Nn / CHUNK)   // 256 chunks per event
#define ASTR 17            // anchor LDS row stride (68B): gcd(17,32)=1 -> all banks
#define CSTR 20            // rep column stride

#define W_ATTR 1.0f
#define W_REP 1.0f
#define W_BPOS 10.0f
#define W_BNEG 3.0f
#define W_BBG 6.0f
#define W_MARG 10.0f
#define ALPHA_F 0.75f

// ---- workspace word offsets ----
// scalars per event (OFF_SCAL + b*32):
//  0 ce0_all  1 rpos_cp  2 rneg_all  3 ce0_bg  4 ncp  5 nbg
//  6 mv(i)    7 ok(i)    8 beta_loss 9 rep_acc 10 attr 11 ce0_cp 12 rneg_cp
#define OFF_SUMF 0                        // [B*K] f  focal sum (k_cplist, atomic)
#define OFF_CNT 2048                      // [B*K] i  cp count  (k_cplist, atomic)
#define OFF_SCAL 4096                     // [B*32]
#define OFF_MODE 4352                     // [1] i
#define ZERO_WORDS 4356                   // memset range
#define OFF_FIRST 4356                    // [B*K] i  (init by k_detect)
#define OFF_CPIDX (OFF_FIRST + Bn*Kk)     // [B*MCAP] i (guarded by mv)
#define OFF_PART (OFF_CPIDX + Bn*MCAP)    // [B*NCH*K*2] f {d2, inst} per block
#define PART_WORDS ((size_t)Bn * NCH * Kk * 2)
#define WS_NEEDED (((size_t)OFF_PART + PART_WORDS) * 4)

// Detect is_cp element width (int32/float32 0-1 words are only {0,1,0x3F800000});
// also initialize the FIRST sentinel (region not read by this kernel).
__global__ void k_detect(const unsigned int* w, int* wsi) {
  const int stride = gridDim.x * blockDim.x;
  const int gid = blockIdx.x * blockDim.x + threadIdx.x;
  for (int i = gid; i < Bn * Kk; i += stride) wsi[OFF_FIRST + i] = 0x7FFFFFFF;
  int bad = 0;
  for (int i = gid; i < (Bn * Nn) / 4; i += stride) {
    unsigned int x = w[i];
    if (x > 1u && x != 0x3F800000u) bad = 1;
  }
  if (bad) atomicOr(&wsi[OFF_MODE], 1);
}

// All cp-point work (~2100 points): cp-side scalar partials (for subtraction),
// per-seg focal/cnt/first, cp-index list. Global atomics are cheap at this rarity.
__global__ __launch_bounds__(256) void k_cplist(const float* __restrict__ beta,
                                                const int* __restrict__ sid,
                                                const void* __restrict__ cpp,
                                                float* wsf, int* wsi) {
  const int mode = wsi[OFF_MODE];
  const int stride = gridDim.x * blockDim.x;
  for (int i = blockIdx.x * blockDim.x + threadIdx.x; i < Bn * Nn; i += stride) {
    bool cp = mode ? (((const unsigned char*)cpp)[i] != 0)
                   : (((const unsigned int*)cpp)[i] != 0u);
    if (cp) {
      const int b = i >> 18;
      const int ii = i & (Nn - 1);
      const float x = beta[i];
      const float p = 1.f / (1.f + __expf(-x));
      const float sp = __logf(1.f + __expf(-fabsf(x)));
      const float ce0 = sp + fmaxf(x, 0.f);
      float* sc = wsf + OFF_SCAL + b * 32;
      atomicAdd(&sc[1], fmaxf(0.8f - p, 0.f));   // rpos (all cp)
      atomicAdd(&sc[4], 1.f);                    // ncp  (all cp)
      atomicAdd(&sc[11], ce0);                   // ce0 over cp (subtract later)
      atomicAdd(&sc[12], fmaxf(p - 0.2f, 0.f));  // rneg over cp (subtract later)
      const int s = sid[i];
      if (s >= 0) {
        const float ce1 = sp + fmaxf(-x, 0.f);
        const float om = 1.f - p;
        atomicAdd(&wsf[OFF_SUMF + b * Kk + s], ALPHA_F * om * om * ce1);
        atomicAdd(&wsi[OFF_CNT + b * Kk + s], 1);
        atomicMin(&wsi[OFF_FIRST + b * Kk + s], ii);
        int pos = atomicAdd(&wsi[OFF_SCAL + b * 32 + 6], 1);
        if (pos < MCAP) wsi[OFF_CPIDX + b * MCAP + pos] = ii;
      }
    }
  }
}

// Main pass: unconditional scalars + per-point d2 vs LDS anchors (gathered inline).
__global__ __launch_bounds__(256, 8) void k_pass(const float* __restrict__ beta,
                                                 const int* __restrict__ sid,
                                                 const float* __restrict__ embed,
                                                 float* wsf, int* wsi, int use_part) {
  const int b = blockIdx.y;
  const int ch = blockIdx.x;
  const int tid = threadIdx.x;
  __shared__ float ls_anch[Kk * ASTR];
  __shared__ float ls_d2[Kk];
  __shared__ int ls_inst[Kk];
  __shared__ float sred[4][4];
  // gather anchors (first-CP embed rows; L3-hot after first block per event)
  {
    const int cnt = wsi[OFF_CNT + b * Kk + tid];
    const int fi = wsi[OFF_FIRST + b * Kk + tid];
    float* dst = &ls_anch[tid * ASTR];
    if (cnt > 0) {
      const float4* src = (const float4*)(embed + ((size_t)b * Nn + (size_t)fi) * Dd);
      float4 v0 = src[0], v1 = src[1], v2 = src[2], v3 = src[3];
      dst[0]=v0.x; dst[1]=v0.y; dst[2]=v0.z; dst[3]=v0.w;
      dst[4]=v1.x; dst[5]=v1.y; dst[6]=v1.z; dst[7]=v1.w;
      dst[8]=v2.x; dst[9]=v2.y; dst[10]=v2.z; dst[11]=v2.w;
      dst[12]=v3.x; dst[13]=v3.y; dst[14]=v3.z; dst[15]=v3.w;
    } else {
      #pragma unroll
      for (int d = 0; d < Dd; ++d) dst[d] = 0.f;
    }
  }
  ls_d2[tid] = 0.f;
  ls_inst[tid] = 0;
  __syncthreads();
  const int base = b * Nn;
  const float* eb = embed + (size_t)base * Dd;
  float a0 = 0.f, a2 = 0.f, a3 = 0.f, a5 = 0.f;
  {
    const int i0 = ch * CHUNK + tid * 4;
    int4 s4 = *(const int4*)(sid + base + i0);
    float4 b4 = *(const float4*)(beta + base + i0);
    float4 ev[16];
    #pragma unroll
    for (int q = 0; q < 16; ++q)
      ev[q] = *(const float4*)(eb + (size_t)(i0 + (q >> 2)) * Dd + (q & 3) * 4);
    const int ss[4] = {s4.x, s4.y, s4.z, s4.w};
    const float xs[4] = {b4.x, b4.y, b4.z, b4.w};
    #pragma unroll
    for (int j = 0; j < 4; ++j) {
      const int s = ss[j];
      const float x = xs[j];
      const float p = 1.f / (1.f + __expf(-x));
      const float sp = __logf(1.f + __expf(-fabsf(x)));
      const float ce0 = sp + fmaxf(x, 0.f);
      a0 += ce0;                       // over ALL points; cp part subtracted later
      a2 += fmaxf(p - 0.2f, 0.f);      // over ALL points; cp part subtracted later
      if (s == -1) { a3 += ce0; a5 += 1.f; }
      const int scl = s >= 0 ? s : 0;
      const float* ar = &ls_anch[scl * ASTR];
      float4 v0 = ev[j * 4], v1 = ev[j * 4 + 1], v2 = ev[j * 4 + 2], v3 = ev[j * 4 + 3];
      float d2 = 0.f, df;
      df = v0.x - ar[0];  d2 += df * df;  df = v0.y - ar[1];  d2 += df * df;
      df = v0.z - ar[2];  d2 += df * df;  df = v0.w - ar[3];  d2 += df * df;
      df = v1.x - ar[4];  d2 += df * df;  df = v1.y - ar[5];  d2 += df * df;
      df = v1.z - ar[6];  d2 += df * df;  df = v1.w - ar[7];  d2 += df * df;
      df = v2.x - ar[8];  d2 += df * df;  df = v2.y - ar[9];  d2 += df * df;
      df = v2.z - ar[10]; d2 += df * df;  df = v2.w - ar[11]; d2 += df * df;
      df = v3.x - ar[12]; d2 += df * df;  df = v3.y - ar[13]; d2 += df * df;
      df = v3.z - ar[14]; d2 += df * df;  df = v3.w - ar[15]; d2 += df * df;
      if (s >= 0) {
        atomicAdd(&ls_inst[s], 1);
        atomicAdd(&ls_d2[s], d2);   // no-cp segs accumulate junk vs zero anchor; masked later
      }
    }
  }
  __syncthreads();
  if (use_part) {
    float2* pb = (float2*)(wsf + OFF_PART + (((size_t)(b * NCH + ch)) * Kk + tid) * 2);
    *pb = make_float2(ls_d2[tid], (float)ls_inst[tid]);
  } else {
    atomicAdd(&wsf[OFF_SCAL + b * 32 + 10], 0.f);  // unreachable in practice (ws is large)
  }
  for (int o = 32; o > 0; o >>= 1) {
    a0 += __shfl_down(a0, o); a2 += __shfl_down(a2, o);
    a3 += __shfl_down(a3, o); a5 += __shfl_down(a5, o);
  }
  const int wv = tid >> 6;
  if ((tid & 63) == 0) {
    sred[wv][0] = a0; sred[wv][1] = a2; sred[wv][2] = a3; sred[wv][3] = a5;
  }
  __syncthreads();
  if (tid == 0) {
    float s0 = 0, s2 = 0, s3 = 0, s5 = 0;
    for (int q = 0; q < 4; ++q) {
      s0 += sred[q][0]; s2 += sred[q][1]; s3 += sred[q][2]; s5 += sred[q][3];
    }
    atomicAdd(&wsf[OFF_SCAL + b * 32 + 0], s0);
    atomicAdd(&wsf[OFF_SCAL + b * 32 + 2], s2);
    atomicAdd(&wsf[OFF_SCAL + b * 32 + 3], s3);
    atomicAdd(&wsf[OFF_SCAL + b * 32 + 5], s5);
  }
}

// Merged partial-reduce + per-event finalize. One block per event.
__global__ __launch_bounds__(256) void k_redev(float* wsf, int* wsi) {
  const int b = blockIdx.x;
  const int t = threadIdx.x;
  const float2* p = (const float2*)(wsf + OFF_PART + (((size_t)b * NCH) * Kk + t) * 2);
  float d2s = 0.f, inst = 0.f;
  for (int ch = 0; ch < NCH; ++ch) {
    float2 v = p[(size_t)ch * Kk];
    d2s += v.x; inst += v.y;
  }
  const int cnt = wsi[OFF_CNT + b * Kk + t];
  const float sumf = wsf[OFF_SUMF + b * Kk + t];
  float attr_p = 0.f, w = 0.f, wf = 0.f;
  if (cnt > 0) {
    attr_p = d2s / fmaxf(inst, 1.f);
    w = inst;
    wf = inst * (sumf / fmaxf((float)cnt, 1.f));
  }
  for (int o = 32; o > 0; o >>= 1) {
    attr_p += __shfl_down(attr_p, o);
    w += __shfl_down(w, o);
    wf += __shfl_down(wf, o);
  }
  __shared__ float r3[3][4];
  if ((t & 63) == 0) { r3[0][t >> 6] = attr_p; r3[1][t >> 6] = w; r3[2][t >> 6] = wf; }
  __syncthreads();
  if (t == 0) {
    float at = r3[0][0] + r3[0][1] + r3[0][2] + r3[0][3];
    float sw = r3[1][0] + r3[1][1] + r3[1][2] + r3[1][3];
    float swf = r3[2][0] + r3[2][1] + r3[2][2] + r3[2][3];
    float pos_bce = swf / fmaxf(sw, 1.f);
    float* sc = wsf + OFF_SCAL + b * 32;
    const float ce0n = sc[0] - sc[11];       // all - cp
    const float rneg_s = sc[2] - sc[12];     // all - cp
    const float rpos = sc[1], ce0b = sc[3], ncp = sc[4], nbg = sc[5];
    const int mv = wsi[OFF_SCAL + b * 32 + 6];
    const float nncp = (float)Nn - ncp;
    const float neg_bce = nncp > 0.f ? ce0n / fmaxf(nncp, 1.f) : 0.f;
    const float pos_m = rpos / fmaxf(ncp, 1.f);
    const float neg_m = nncp > 0.f ? rneg_s / fmaxf(nncp, 1.f) : 0.f;
    const float bg_bce = nbg > 0.f ? ce0b / fmaxf(nbg, 1.f) : 0.f;
    sc[8] = W_BPOS * pos_bce + W_BNEG * neg_bce + W_BBG * bg_bce + W_MARG * (pos_m + neg_m);
    sc[10] = at;
    const float nvalid = (float)Nn - nbg;
    wsi[OFF_SCAL + b * 32 + 7] = (nvalid > 0.f && mv > 0) ? 1 : 0;
  }
}

__global__ __launch_bounds__(256) void k_rep(const float* __restrict__ embed,
                                             float* wsf, int* wsi) {
  const int b = blockIdx.y;
  const int t = threadIdx.x;
  __shared__ int sidx[MCAP];
  __shared__ float cemb[256 * CSTR];
  __shared__ float csq[256];
  __shared__ float red[4];
  const int mv = wsi[OFF_SCAL + b * 32 + 6];
  const int msel = mv < MSEL ? mv : MSEL;
  const int mload = mv < MCAP ? mv : MCAP;
  for (int i = t; i < MCAP; i += 256)
    sidx[i] = (i < mload) ? wsi[OFF_CPIDX + b * MCAP + i] : 0x7FFFFFFF;
  __syncthreads();
  if (mv > MSEL) {
    for (int ksz = 2; ksz <= MCAP; ksz <<= 1) {
      for (int j = ksz >> 1; j > 0; j >>= 1) {
        for (int e = t; e < MCAP; e += 256) {
          int ixj = e ^ j;
          if (ixj > e) {
            bool up = ((e & ksz) == 0);
            int x = sidx[e], y = sidx[ixj];
            if ((x > y) == up) { sidx[e] = y; sidx[ixj] = x; }
          }
        }
        __syncthreads();
      }
    }
  }
  const float* eb = embed + (size_t)b * Nn * Dd;
  const int row = blockIdx.x * 64 + (t & 63);
  const int cg = t >> 6;
  const bool rok = row < msel;
  float r[Dd];
  float rsq = 0.f;
  if (rok) {
    const float4* s = (const float4*)(eb + (size_t)sidx[row] * Dd);
    float4 v0 = s[0], v1 = s[1], v2 = s[2], v3 = s[3];
    r[0]=v0.x; r[1]=v0.y; r[2]=v0.z; r[3]=v0.w;
    r[4]=v1.x; r[5]=v1.y; r[6]=v1.z; r[7]=v1.w;
    r[8]=v2.x; r[9]=v2.y; r[10]=v2.z; r[11]=v2.w;
    r[12]=v3.x; r[13]=v3.y; r[14]=v3.z; r[15]=v3.w;
    #pragma unroll
    for (int d = 0; d < Dd; ++d) rsq += r[d] * r[d];
  }
  float acc = 0.f;
  for (int c0 = 0; c0 < msel; c0 += 256) {
    const int nc = (msel - c0) < 256 ? (msel - c0) : 256;
    __syncthreads();
    for (int wvi = t; wvi < nc * 4; wvi += 256) {
      int col = wvi >> 2, q = wvi & 3;
      float4 v = ((const float4*)(eb + (size_t)sidx[c0 + col] * Dd))[q];
      *(float4*)&cemb[col * CSTR + q * 4] = v;
    }
    __syncthreads();
    for (int col = t; col < nc; col += 256) {
      float s = 0.f;
      #pragma unroll
      for (int d = 0; d < Dd; ++d) s += cemb[col * CSTR + d] * cemb[col * CSTR + d];
      csq[col] = s;
    }
    __syncthreads();
    if (rok) {
      for (int c = cg; c < nc; c += 4) {
        float dotrc = 0.f;
        #pragma unroll
        for (int d = 0; d < Dd; ++d) dotrc += r[d] * cemb[c * CSTR + d];
        acc += __expf(2.f * dotrc - rsq - csq[c]);
      }
    }
  }
  for (int o = 32; o > 0; o >>= 1) acc += __shfl_down(acc, o);
  if ((t & 63) == 0) red[t >> 6] = acc;
  __syncthreads();
  if (t == 0) {
    float s = red[0] + red[1] + red[2] + red[3];
    if (s != 0.f) atomicAdd(&wsf[OFF_SCAL + b * 32 + 9], s);
  }
}

__global__ void k_final(float* wsf, int* wsi, float* out, int out_size) {
  const int t = threadIdx.x;
  if (t == 0) {
    float total = 0.f;
    int cnt = 0;
    for (int b = 0; b < Bn; ++b) {
      float* sc = wsf + OFF_SCAL + b * 32;
      int* sci = wsi + OFF_SCAL + b * 32;
      int mv = sci[6];
      if (sci[7]) {
        float mvf = (float)mv;
        float rep = (mv > 1) ? W_REP * sc[9] / fmaxf(mvf * mvf, 1.f) : 0.f;
        total += sc[8] + W_ATTR * sc[10] + rep;
        cnt++;
      }
    }
    out[0] = (cnt > 0) ? total / (float)cnt : 0.f;
  }
  for (int i = 1 + t; i < out_size; i += 256) out[i] = 0.f;
}

extern "C" void kernel_launch(void* const* d_in, const int* in_sizes, int n_in,
                              void* d_out, int out_size, void* d_ws, size_t ws_size,
                              hipStream_t stream) {
  const float* beta = (const float*)d_in[0];
  const float* embed = (const float*)d_in[1];
  const int* sid = (const int*)d_in[2];
  const void* cp = d_in[3];
  float* out = (float*)d_out;
  float* wsf = (float*)d_ws;
  int* wsi = (int*)d_ws;
  const int use_part = ws_size >= WS_NEEDED ? 1 : 0;

  hipMemsetAsync(d_ws, 0, (size_t)ZERO_WORDS * 4, stream);
  k_detect<<<256, 256, 0, stream>>>((const unsigned int*)cp, wsi);
  k_cplist<<<2048, 256, 0, stream>>>(beta, sid, cp, wsf, wsi);
  dim3 gp(NCH, Bn);
  k_pass<<<gp, 256, 0, stream>>>(beta, sid, embed, wsf, wsi, use_part);
  k_redev<<<Bn, 256, 0, stream>>>(wsf, wsi);
  dim3 gr(MSEL / 64, Bn);
  k_rep<<<gr, 256, 0, stream>>>(embed, wsf, wsi);
  k_final<<<1, 256, 0, stream>>>(wsf, wsi, out, out_size);
}

// Round 6
// 293.530 us; speedup vs baseline: 1.0849x; 1.0849x over previous
//
#include <hip/hip_runtime.h>
#include <math.h>

#define Bn 8
#define Nn 262144
#define Kk 256
#define Dd 16
#define MCAP 4096
#define MSEL 1024
#define CHUNK 2048
#define NCH (Nn / CHUNK)   // 128 chunks per event
#define CSTR 20            // rep column stride

#define W_ATTR 1.0f
#define W_REP 1.0f
#define W_BPOS 10.0f
#define W_BNEG 3.0f
#define W_BBG 6.0f
#define W_MARG 10.0f
#define ALPHA_F 0.75f

// ---- workspace word offsets ----
// scalars per event (OFF_SCAL + b*32):
//  0 ce0_all  1 rpos_cp  2 rneg_all  3 ce0_bg  4 ncp  5 nbg
//  6 mv(i)    7 ok(i)    8 beta_loss 9 rep_acc 10 attr 11 ce0_cp 12 rneg_cp
#define OFF_SUMF 0                        // [B*K] f  focal sum (k_cplist, atomic)
#define OFF_CNT 2048                      // [B*K] i  cp count  (k_cplist, atomic)
#define OFF_D2F 4096                      // [B*K] f  fallback d2 (atomic, only if !use_part)
#define OFF_INSTF 6144                    // [B*K] i  fallback inst
#define OFF_SCAL 8192                     // [B*32]
#define OFF_MODE 8448                     // [1] i
#define ZERO_WORDS 8452
#define OFF_FIRST 8464                    // [B*K] i (init by k_detect)
#define OFF_ANCH (OFF_FIRST + Bn*Kk)      // [B*D*K] f TRANSPOSED anchors: [b*4096 + d*256 + s]
#define OFF_CPIDX (OFF_ANCH + Bn*Kk*Dd)   // [B*MCAP] i
#define OFF_PART (OFF_CPIDX + Bn*MCAP)    // [B*NCH*K*2] f {d2, inst} per block
#define PART_WORDS ((size_t)Bn * NCH * Kk * 2)
#define WS_NEEDED (((size_t)OFF_PART + PART_WORDS) * 4)

// Detect is_cp element width (int32/float32 0/1 words are only {0,1,0x3F800000});
// also init the FIRST sentinel.
__global__ void k_detect(const uint4* w4, int* wsi) {
  const int stride = gridDim.x * blockDim.x;
  const int gid = blockIdx.x * blockDim.x + threadIdx.x;
  for (int i = gid; i < Bn * Kk; i += stride) wsi[OFF_FIRST + i] = 0x7FFFFFFF;
  int bad = 0;
  for (int i = gid; i < (Bn * Nn) / 16; i += stride) {
    uint4 u = w4[i];
    if ((u.x > 1u && u.x != 0x3F800000u) || (u.y > 1u && u.y != 0x3F800000u) ||
        (u.z > 1u && u.z != 0x3F800000u) || (u.w > 1u && u.w != 0x3F800000u)) bad = 1;
  }
  if (bad) atomicOr(&wsi[OFF_MODE], 1);
}

// All cp-point work (~2100 points): cp-side scalar partials (subtracted later),
// per-seg focal/cnt/first, cp-index list.
__global__ __launch_bounds__(256) void k_cplist(const float* __restrict__ beta,
                                                const int* __restrict__ sid,
                                                const void* __restrict__ cpp,
                                                float* wsf, int* wsi) {
  const int mode = wsi[OFF_MODE];
  const int stride = gridDim.x * blockDim.x;
  for (int i = blockIdx.x * blockDim.x + threadIdx.x; i < Bn * Nn; i += stride) {
    bool cp = mode ? (((const unsigned char*)cpp)[i] != 0)
                   : (((const unsigned int*)cpp)[i] != 0u);
    if (cp) {
      const int b = i >> 18;
      const int ii = i & (Nn - 1);
      const float x = beta[i];
      const float p = 1.f / (1.f + __expf(-x));
      const float sp = __logf(1.f + __expf(-fabsf(x)));
      const float ce0 = sp + fmaxf(x, 0.f);
      float* sc = wsf + OFF_SCAL + b * 32;
      atomicAdd(&sc[1], fmaxf(0.8f - p, 0.f));   // rpos (all cp)
      atomicAdd(&sc[4], 1.f);                    // ncp
      atomicAdd(&sc[11], ce0);                   // ce0 over cp (subtract later)
      atomicAdd(&sc[12], fmaxf(p - 0.2f, 0.f));  // rneg over cp (subtract later)
      const int s = sid[i];
      if (s >= 0) {
        const float ce1 = sp + fmaxf(-x, 0.f);
        const float om = 1.f - p;
        atomicAdd(&wsf[OFF_SUMF + b * Kk + s], ALPHA_F * om * om * ce1);
        atomicAdd(&wsi[OFF_CNT + b * Kk + s], 1);
        atomicMin(&wsi[OFF_FIRST + b * Kk + s], ii);
        int pos = atomicAdd(&wsi[OFF_SCAL + b * 32 + 6], 1);
        if (pos < MCAP) wsi[OFF_CPIDX + b * MCAP + pos] = ii;
      }
    }
  }
}

// Build TRANSPOSED anchor table: anchT[b][d][s] = embed[b, first[s], d] (0 if no cp).
// Lane t writes word d*256+t per d -> coalesced.
__global__ __launch_bounds__(256) void k_anchor(const float* __restrict__ embed,
                                                float* wsf, int* wsi) {
  const int b = blockIdx.x;
  const int t = threadIdx.x;
  const int cnt = wsi[OFF_CNT + b * Kk + t];
  const int fi = wsi[OFF_FIRST + b * Kk + t];
  float v[Dd];
  if (cnt > 0) {
    const float4* src = (const float4*)(embed + ((size_t)b * Nn + (size_t)fi) * Dd);
    float4 v0 = src[0], v1 = src[1], v2 = src[2], v3 = src[3];
    v[0]=v0.x; v[1]=v0.y; v[2]=v0.z; v[3]=v0.w;
    v[4]=v1.x; v[5]=v1.y; v[6]=v1.z; v[7]=v1.w;
    v[8]=v2.x; v[9]=v2.y; v[10]=v2.z; v[11]=v2.w;
    v[12]=v3.x; v[13]=v3.y; v[14]=v3.z; v[15]=v3.w;
  } else {
    #pragma unroll
    for (int d = 0; d < Dd; ++d) v[d] = 0.f;
  }
  float* dst = wsf + OFF_ANCH + (size_t)b * (Kk * Dd);
  #pragma unroll
  for (int d = 0; d < Dd; ++d) dst[d * Kk + t] = v[d];
}

// Main pass: unconditional scalars + per-point d2 vs transposed LDS anchors.
// Anchor read ls_anchT[d*256+s]: bank = s%32, random s -> ~2 lanes/bank (free).
__global__ __launch_bounds__(256, 8) void k_pass(const float* __restrict__ beta,
                                                 const int* __restrict__ sid,
                                                 const float* __restrict__ embed,
                                                 float* wsf, int* wsi, int use_part) {
  const int b = blockIdx.y;
  const int ch = blockIdx.x;
  const int tid = threadIdx.x;
  __shared__ float ls_anchT[Kk * Dd];   // 16 KB, [d][s]
  __shared__ float ls_d2[Kk];
  __shared__ int ls_inst[Kk];
  __shared__ float sred[4][4];
  // stage anchor table: contiguous, coalesced (float4 q-major)
  {
    const float4* src = (const float4*)(wsf + OFF_ANCH + (size_t)b * (Kk * Dd));
    float4* dst = (float4*)ls_anchT;
    #pragma unroll
    for (int q = 0; q < 4; ++q) dst[q * 256 + tid] = src[q * 256 + tid];
  }
  ls_d2[tid] = 0.f;
  ls_inst[tid] = 0;
  __syncthreads();
  const int base = b * Nn;
  const float* eb = embed + (size_t)base * Dd;
  float a0 = 0.f, a2 = 0.f, a3 = 0.f, a5 = 0.f;
  for (int it = 0; it < CHUNK / 1024; ++it) {
    const int i0 = ch * CHUNK + it * 1024 + tid * 4;
    int4 s4 = *(const int4*)(sid + base + i0);
    float4 b4 = *(const float4*)(beta + base + i0);
    float4 ev[16];
    #pragma unroll
    for (int q = 0; q < 16; ++q)
      ev[q] = *(const float4*)(eb + (size_t)(i0 + (q >> 2)) * Dd + (q & 3) * 4);
    const int ss[4] = {s4.x, s4.y, s4.z, s4.w};
    const float xs[4] = {b4.x, b4.y, b4.z, b4.w};
    #pragma unroll
    for (int j = 0; j < 4; ++j) {
      const int s = ss[j];
      const float x = xs[j];
      const float p = 1.f / (1.f + __expf(-x));
      const float sp = __logf(1.f + __expf(-fabsf(x)));
      const float ce0 = sp + fmaxf(x, 0.f);
      a0 += ce0;                       // cp part subtracted in k_redev
      a2 += fmaxf(p - 0.2f, 0.f);      // cp part subtracted in k_redev
      if (s == -1) { a3 += ce0; a5 += 1.f; }
      const int scl = s >= 0 ? s : 0;
      const float* e = (const float*)&ev[j * 4];
      float d2 = 0.f;
      #pragma unroll
      for (int d = 0; d < Dd; ++d) {
        float df = e[d] - ls_anchT[d * Kk + scl];
        d2 += df * df;
      }
      if (s >= 0) {
        atomicAdd(&ls_inst[s], 1);
        atomicAdd(&ls_d2[s], d2);   // no-cp segs accumulate junk vs zero anchor; masked later
      }
    }
  }
  __syncthreads();
  if (use_part) {
    float2* pb = (float2*)(wsf + OFF_PART + (((size_t)(b * NCH + ch)) * Kk + tid) * 2);
    *pb = make_float2(ls_d2[tid], (float)ls_inst[tid]);
  } else {
    atomicAdd(&wsf[OFF_D2F + b * Kk + tid], ls_d2[tid]);
    atomicAdd(&wsi[OFF_INSTF + b * Kk + tid], ls_inst[tid]);
  }
  for (int o = 32; o > 0; o >>= 1) {
    a0 += __shfl_down(a0, o); a2 += __shfl_down(a2, o);
    a3 += __shfl_down(a3, o); a5 += __shfl_down(a5, o);
  }
  const int wv = tid >> 6;
  if ((tid & 63) == 0) {
    sred[wv][0] = a0; sred[wv][1] = a2; sred[wv][2] = a3; sred[wv][3] = a5;
  }
  __syncthreads();
  if (tid == 0) {
    float s0 = 0, s2 = 0, s3 = 0, s5 = 0;
    for (int q = 0; q < 4; ++q) {
      s0 += sred[q][0]; s2 += sred[q][1]; s3 += sred[q][2]; s5 += sred[q][3];
    }
    atomicAdd(&wsf[OFF_SCAL + b * 32 + 0], s0);
    atomicAdd(&wsf[OFF_SCAL + b * 32 + 2], s2);
    atomicAdd(&wsf[OFF_SCAL + b * 32 + 3], s3);
    atomicAdd(&wsf[OFF_SCAL + b * 32 + 5], s5);
  }
}

// Merged partial-reduce + per-event finalize. One block per event.
__global__ __launch_bounds__(256) void k_redev(float* wsf, int* wsi, int use_part) {
  const int b = blockIdx.x;
  const int t = threadIdx.x;
  float d2s, inst;
  if (use_part) {
    const float2* p = (const float2*)(wsf + OFF_PART + (((size_t)b * NCH) * Kk + t) * 2);
    d2s = 0.f; inst = 0.f;
    for (int ch = 0; ch < NCH; ++ch) {
      float2 v = p[(size_t)ch * Kk];
      d2s += v.x; inst += v.y;
    }
  } else {
    d2s = wsf[OFF_D2F + b * Kk + t];
    inst = (float)wsi[OFF_INSTF + b * Kk + t];
  }
  const int cnt = wsi[OFF_CNT + b * Kk + t];
  const float sumf = wsf[OFF_SUMF + b * Kk + t];
  float attr_p = 0.f, w = 0.f, wf = 0.f;
  if (cnt > 0) {
    attr_p = d2s / fmaxf(inst, 1.f);
    w = inst;
    wf = inst * (sumf / fmaxf((float)cnt, 1.f));
  }
  for (int o = 32; o > 0; o >>= 1) {
    attr_p += __shfl_down(attr_p, o);
    w += __shfl_down(w, o);
    wf += __shfl_down(wf, o);
  }
  __shared__ float r3[3][4];
  if ((t & 63) == 0) { r3[0][t >> 6] = attr_p; r3[1][t >> 6] = w; r3[2][t >> 6] = wf; }
  __syncthreads();
  if (t == 0) {
    float at = r3[0][0] + r3[0][1] + r3[0][2] + r3[0][3];
    float sw = r3[1][0] + r3[1][1] + r3[1][2] + r3[1][3];
    float swf = r3[2][0] + r3[2][1] + r3[2][2] + r3[2][3];
    float pos_bce = swf / fmaxf(sw, 1.f);
    float* sc = wsf + OFF_SCAL + b * 32;
    const float ce0n = sc[0] - sc[11];
    const float rneg_s = sc[2] - sc[12];
    const float rpos = sc[1], ce0b = sc[3], ncp = sc[4], nbg = sc[5];
    const int mv = wsi[OFF_SCAL + b * 32 + 6];
    const float nncp = (float)Nn - ncp;
    const float neg_bce = nncp > 0.f ? ce0n / fmaxf(nncp, 1.f) : 0.f;
    const float pos_m = rpos / fmaxf(ncp, 1.f);
    const float neg_m = nncp > 0.f ? rneg_s / fmaxf(nncp, 1.f) : 0.f;
    const float bg_bce = nbg > 0.f ? ce0b / fmaxf(nbg, 1.f) : 0.f;
    sc[8] = W_BPOS * pos_bce + W_BNEG * neg_bce + W_BBG * bg_bce + W_MARG * (pos_m + neg_m);
    sc[10] = at;
    const float nvalid = (float)Nn - nbg;
    wsi[OFF_SCAL + b * 32 + 7] = (nvalid > 0.f && mv > 0) ? 1 : 0;
  }
}

__global__ __launch_bounds__(256) void k_rep(const float* __restrict__ embed,
                                             float* wsf, int* wsi) {
  const int b = blockIdx.y;
  const int t = threadIdx.x;
  __shared__ int sidx[MCAP];
  __shared__ float cemb[256 * CSTR];
  __shared__ float csq[256];
  __shared__ float red[4];
  const int mv = wsi[OFF_SCAL + b * 32 + 6];
  const int msel = mv < MSEL ? mv : MSEL;
  const int mload = mv < MCAP ? mv : MCAP;
  for (int i = t; i < MCAP; i += 256)
    sidx[i] = (i < mload) ? wsi[OFF_CPIDX + b * MCAP + i] : 0x7FFFFFFF;
  __syncthreads();
  if (mv > MSEL) {
    for (int ksz = 2; ksz <= MCAP; ksz <<= 1) {
      for (int j = ksz >> 1; j > 0; j >>= 1) {
        for (int e = t; e < MCAP; e += 256) {
          int ixj = e ^ j;
          if (ixj > e) {
            bool up = ((e & ksz) == 0);
            int x = sidx[e], y = sidx[ixj];
            if ((x > y) == up) { sidx[e] = y; sidx[ixj] = x; }
          }
        }
        __syncthreads();
      }
    }
  }
  const float* eb = embed + (size_t)b * Nn * Dd;
  const int row = blockIdx.x * 64 + (t & 63);
  const int cg = t >> 6;
  const bool rok = row < msel;
  float r[Dd];
  float rsq = 0.f;
  if (rok) {
    const float4* s = (const float4*)(eb + (size_t)sidx[row] * Dd);
    float4 v0 = s[0], v1 = s[1], v2 = s[2], v3 = s[3];
    r[0]=v0.x; r[1]=v0.y; r[2]=v0.z; r[3]=v0.w;
    r[4]=v1.x; r[5]=v1.y; r[6]=v1.z; r[7]=v1.w;
    r[8]=v2.x; r[9]=v2.y; r[10]=v2.z; r[11]=v2.w;
    r[12]=v3.x; r[13]=v3.y; r[14]=v3.z; r[15]=v3.w;
    #pragma unroll
    for (int d = 0; d < Dd; ++d) rsq += r[d] * r[d];
  }
  float acc = 0.f;
  for (int c0 = 0; c0 < msel; c0 += 256) {
    const int nc = (msel - c0) < 256 ? (msel - c0) : 256;
    __syncthreads();
    for (int wvi = t; wvi < nc * 4; wvi += 256) {
      int col = wvi >> 2, q = wvi & 3;
      float4 v = ((const float4*)(eb + (size_t)sidx[c0 + col] * Dd))[q];
      *(float4*)&cemb[col * CSTR + q * 4] = v;
    }
    __syncthreads();
    for (int col = t; col < nc; col += 256) {
      float s = 0.f;
      #pragma unroll
      for (int d = 0; d < Dd; ++d) s += cemb[col * CSTR + d] * cemb[col * CSTR + d];
      csq[col] = s;
    }
    __syncthreads();
    if (rok) {
      for (int c = cg; c < nc; c += 4) {
        float dotrc = 0.f;
        #pragma unroll
        for (int d = 0; d < Dd; ++d) dotrc += r[d] * cemb[c * CSTR + d];
        acc += __expf(2.f * dotrc - rsq - csq[c]);
      }
    }
  }
  for (int o = 32; o > 0; o >>= 1) acc += __shfl_down(acc, o);
  if ((t & 63) == 0) red[t >> 6] = acc;
  __syncthreads();
  if (t == 0) {
    float s = red[0] + red[1] + red[2] + red[3];
    if (s != 0.f) atomicAdd(&wsf[OFF_SCAL + b * 32 + 9], s);
  }
}

__global__ void k_final(float* wsf, int* wsi, float* out, int out_size) {
  const int t = threadIdx.x;
  if (t == 0) {
    float total = 0.f;
    int cnt = 0;
    for (int b = 0; b < Bn; ++b) {
      float* sc = wsf + OFF_SCAL + b * 32;
      int* sci = wsi + OFF_SCAL + b * 32;
      int mv = sci[6];
      if (sci[7]) {
        float mvf = (float)mv;
        float rep = (mv > 1) ? W_REP * sc[9] / fmaxf(mvf * mvf, 1.f) : 0.f;
        total += sc[8] + W_ATTR * sc[10] + rep;
        cnt++;
      }
    }
    out[0] = (cnt > 0) ? total / (float)cnt : 0.f;
  }
  for (int i = 1 + t; i < out_size; i += 256) out[i] = 0.f;
}

extern "C" void kernel_launch(void* const* d_in, const int* in_sizes, int n_in,
                              void* d_out, int out_size, void* d_ws, size_t ws_size,
                              hipStream_t stream) {
  const float* beta = (const float*)d_in[0];
  const float* embed = (const float*)d_in[1];
  const int* sid = (const int*)d_in[2];
  const void* cp = d_in[3];
  float* out = (float*)d_out;
  float* wsf = (float*)d_ws;
  int* wsi = (int*)d_ws;
  const int use_part = ws_size >= WS_NEEDED ? 1 : 0;

  hipMemsetAsync(d_ws, 0, (size_t)ZERO_WORDS * 4, stream);
  k_detect<<<256, 256, 0, stream>>>((const uint4*)cp, wsi);
  k_cplist<<<2048, 256, 0, stream>>>(beta, sid, cp, wsf, wsi);
  k_anchor<<<Bn, 256, 0, stream>>>(embed, wsf, wsi);
  dim3 gp(NCH, Bn);
  k_pass<<<gp, 256, 0, stream>>>(beta, sid, embed, wsf, wsi, use_part);
  k_redev<<<Bn, 256, 0, stream>>>(wsf, wsi, use_part);
  dim3 gr(MSEL / 64, Bn);
  k_rep<<<gr, 256, 0, stream>>>(embed, wsf, wsi);
  k_final<<<1, 256, 0, stream>>>(wsf, wsi, out, out_size);
}

// Round 8
// 281.446 us; speedup vs baseline: 1.1315x; 1.0429x over previous
//
#include <hip/hip_runtime.h>
#include <math.h>

#define Bn 8
#define Nn 262144
#define Kk 256
#define Dd 16
#define MCAP 4096
#define MSEL 1024
#define CHUNK 2048
#define NCH (Nn / CHUNK)   // 128 chunks per event
#define CSTR 20            // rep column stride

#define W_ATTR 1.0f
#define W_REP 1.0f
#define W_BPOS 10.0f
#define W_BNEG 3.0f
#define W_BBG 6.0f
#define W_MARG 10.0f
#define ALPHA_F 0.75f

// ---- workspace word offsets ----
// scalars per event (OFF_SCAL + b*32):
//  0 ce0_all  1 rpos_cp  2 rneg_all  3 ce0_bg  4 ncp  5 nbg
//  6 mv(i)    7 ok(i)    8 beta_loss 9 rep_acc 10 attr 11 ce0_cp 12 rneg_cp
#define OFF_SUMF 0                        // [B*K] f  focal sum (k_cplist, atomic)
#define OFF_CNT 2048                      // [B*K] i  cp count  (k_cplist, atomic)
#define OFF_D2F 4096                      // [B*K] f  fallback d2 (atomic, only if !use_part)
#define OFF_INSTF 6144                    // [B*K] i  fallback inst
#define OFF_SCAL 8192                     // [B*32]
#define OFF_MODE 8448                     // [1] i
#define ZERO_WORDS 8452
#define OFF_FIRST 8464                    // [B*K] i (init by k_detect)
#define OFF_ANCH (OFF_FIRST + Bn*Kk)      // [B*D*K] f TRANSPOSED anchors: [b*4096 + d*256 + s]
#define OFF_CPIDX (OFF_ANCH + Bn*Kk*Dd)   // [B*MCAP] i
#define OFF_PART (OFF_CPIDX + Bn*MCAP)    // [B*NCH*K*2] f {d2, inst} per block
#define PART_WORDS ((size_t)Bn * NCH * Kk * 2)
#define WS_NEEDED (((size_t)OFF_PART + PART_WORDS) * 4)

// Detect is_cp element width (int32/float32 0/1 words are only {0,1,0x3F800000});
// also init the FIRST sentinel.
__global__ void k_detect(const uint4* w4, int* wsi) {
  const int stride = gridDim.x * blockDim.x;
  const int gid = blockIdx.x * blockDim.x + threadIdx.x;
  for (int i = gid; i < Bn * Kk; i += stride) wsi[OFF_FIRST + i] = 0x7FFFFFFF;
  int bad = 0;
  for (int i = gid; i < (Bn * Nn) / 16; i += stride) {
    uint4 u = w4[i];
    if ((u.x > 1u && u.x != 0x3F800000u) || (u.y > 1u && u.y != 0x3F800000u) ||
        (u.z > 1u && u.z != 0x3F800000u) || (u.w > 1u && u.w != 0x3F800000u)) bad = 1;
  }
  if (bad) atomicOr(&wsi[OFF_MODE], 1);
}

// All cp-point work (~2100 points): cp-side scalar partials (subtracted later),
// per-seg focal/cnt/first, cp-index list.
__global__ __launch_bounds__(256) void k_cplist(const float* __restrict__ beta,
                                                const int* __restrict__ sid,
                                                const void* __restrict__ cpp,
                                                float* wsf, int* wsi) {
  const int mode = wsi[OFF_MODE];
  const int stride = gridDim.x * blockDim.x;
  for (int i = blockIdx.x * blockDim.x + threadIdx.x; i < Bn * Nn; i += stride) {
    bool cp = mode ? (((const unsigned char*)cpp)[i] != 0)
                   : (((const unsigned int*)cpp)[i] != 0u);
    if (cp) {
      const int b = i >> 18;
      const int ii = i & (Nn - 1);
      const float x = beta[i];
      const float p = 1.f / (1.f + __expf(-x));
      const float sp = __logf(1.f + __expf(-fabsf(x)));
      const float ce0 = sp + fmaxf(x, 0.f);
      float* sc = wsf + OFF_SCAL + b * 32;
      atomicAdd(&sc[1], fmaxf(0.8f - p, 0.f));   // rpos (all cp)
      atomicAdd(&sc[4], 1.f);                    // ncp
      atomicAdd(&sc[11], ce0);                   // ce0 over cp (subtract later)
      atomicAdd(&sc[12], fmaxf(p - 0.2f, 0.f));  // rneg over cp (subtract later)
      const int s = sid[i];
      if (s >= 0) {
        const float ce1 = sp + fmaxf(-x, 0.f);
        const float om = 1.f - p;
        atomicAdd(&wsf[OFF_SUMF + b * Kk + s], ALPHA_F * om * om * ce1);
        atomicAdd(&wsi[OFF_CNT + b * Kk + s], 1);
        atomicMin(&wsi[OFF_FIRST + b * Kk + s], ii);
        int pos = atomicAdd(&wsi[OFF_SCAL + b * 32 + 6], 1);
        if (pos < MCAP) wsi[OFF_CPIDX + b * MCAP + pos] = ii;
      }
    }
  }
}

// Build TRANSPOSED anchor table: anchT[b][d][s] = embed[b, first[s], d] (0 if no cp).
__global__ __launch_bounds__(256) void k_anchor(const float* __restrict__ embed,
                                                float* wsf, int* wsi) {
  const int b = blockIdx.x;
  const int t = threadIdx.x;
  const int cnt = wsi[OFF_CNT + b * Kk + t];
  const int fi = wsi[OFF_FIRST + b * Kk + t];
  float v[Dd];
  if (cnt > 0) {
    const float4* src = (const float4*)(embed + ((size_t)b * Nn + (size_t)fi) * Dd);
    float4 v0 = src[0], v1 = src[1], v2 = src[2], v3 = src[3];
    v[0]=v0.x; v[1]=v0.y; v[2]=v0.z; v[3]=v0.w;
    v[4]=v1.x; v[5]=v1.y; v[6]=v1.z; v[7]=v1.w;
    v[8]=v2.x; v[9]=v2.y; v[10]=v2.z; v[11]=v2.w;
    v[12]=v3.x; v[13]=v3.y; v[14]=v3.z; v[15]=v3.w;
  } else {
    #pragma unroll
    for (int d = 0; d < Dd; ++d) v[d] = 0.f;
  }
  float* dst = wsf + OFF_ANCH + (size_t)b * (Kk * Dd);
  #pragma unroll
  for (int d = 0; d < Dd; ++d) dst[d * Kk + t] = v[d];
}

// Main pass. __launch_bounds__(256,4): VGPR cap 128 so the 16x float4 embed
// batch stays in registers and ALL loads issue before the first use (MLP).
// Grid is 4 blocks/CU anyway, so requesting more waves costs MLP for nothing.
__global__ __launch_bounds__(256, 4) void k_pass(const float* __restrict__ beta,
                                                 const int* __restrict__ sid,
                                                 const float* __restrict__ embed,
                                                 float* wsf, int* wsi, int use_part) {
  const int b = blockIdx.y;
  const int ch = blockIdx.x;
  const int tid = threadIdx.x;
  __shared__ float ls_anchT[Kk * Dd];   // 16 KB, [d][s]
  __shared__ float ls_d2[Kk];
  __shared__ int ls_inst[Kk];
  __shared__ float sred[4][4];
  // stage anchor table: contiguous, coalesced
  {
    const float4* src = (const float4*)(wsf + OFF_ANCH + (size_t)b * (Kk * Dd));
    float4* dst = (float4*)ls_anchT;
    #pragma unroll
    for (int q = 0; q < 4; ++q) dst[q * 256 + tid] = src[q * 256 + tid];
  }
  ls_d2[tid] = 0.f;
  ls_inst[tid] = 0;
  __syncthreads();
  const int base = b * Nn;
  const float* eb = embed + (size_t)base * Dd;
  float a0 = 0.f, a2 = 0.f, a3 = 0.f, a5 = 0.f;
  for (int it = 0; it < CHUNK / 1024; ++it) {
    const int i0 = ch * CHUNK + it * 1024 + tid * 4;
    int4 s4 = *(const int4*)(sid + base + i0);
    float4 b4 = *(const float4*)(beta + base + i0);
    float4 ev[16];
    #pragma unroll
    for (int q = 0; q < 16; ++q)
      ev[q] = *(const float4*)(eb + (size_t)(i0 + (q >> 2)) * Dd + (q & 3) * 4);
    const int ss[4] = {s4.x, s4.y, s4.z, s4.w};
    const float xs[4] = {b4.x, b4.y, b4.z, b4.w};
    #pragma unroll
    for (int j = 0; j < 4; ++j) {
      const int s = ss[j];
      const float x = xs[j];
      const float p = 1.f / (1.f + __expf(-x));
      const float sp = __logf(1.f + __expf(-fabsf(x)));
      const float ce0 = sp + fmaxf(x, 0.f);
      a0 += ce0;                       // cp part subtracted in k_redev
      a2 += fmaxf(p - 0.2f, 0.f);      // cp part subtracted in k_redev
      if (s == -1) { a3 += ce0; a5 += 1.f; }
      const int scl = s >= 0 ? s : 0;
      const float* e = (const float*)&ev[j * 4];
      float d2 = 0.f;
      #pragma unroll
      for (int d = 0; d < Dd; ++d) {
        float df = e[d] - ls_anchT[d * Kk + scl];
        d2 += df * df;
      }
      if (s >= 0) {
        atomicAdd(&ls_inst[s], 1);
        atomicAdd(&ls_d2[s], d2);   // no-cp segs accumulate junk vs zero anchor; masked later
      }
    }
  }
  __syncthreads();
  if (use_part) {
    float2* pb = (float2*)(wsf + OFF_PART + (((size_t)(b * NCH + ch)) * Kk + tid) * 2);
    *pb = make_float2(ls_d2[tid], (float)ls_inst[tid]);
  } else {
    atomicAdd(&wsf[OFF_D2F + b * Kk + tid], ls_d2[tid]);
    atomicAdd(&wsi[OFF_INSTF + b * Kk + tid], ls_inst[tid]);
  }
  for (int o = 32; o > 0; o >>= 1) {
    a0 += __shfl_down(a0, o); a2 += __shfl_down(a2, o);
    a3 += __shfl_down(a3, o); a5 += __shfl_down(a5, o);
  }
  const int wv = tid >> 6;
  if ((tid & 63) == 0) {
    sred[wv][0] = a0; sred[wv][1] = a2; sred[wv][2] = a3; sred[wv][3] = a5;
  }
  __syncthreads();
  if (tid == 0) {
    float s0 = 0, s2 = 0, s3 = 0, s5 = 0;
    for (int q = 0; q < 4; ++q) {
      s0 += sred[q][0]; s2 += sred[q][1]; s3 += sred[q][2]; s5 += sred[q][3];
    }
    atomicAdd(&wsf[OFF_SCAL + b * 32 + 0], s0);
    atomicAdd(&wsf[OFF_SCAL + b * 32 + 2], s2);
    atomicAdd(&wsf[OFF_SCAL + b * 32 + 3], s3);
    atomicAdd(&wsf[OFF_SCAL + b * 32 + 5], s5);
  }
}

// Merged partial-reduce + per-event finalize. One block per event.
__global__ __launch_bounds__(256) void k_redev(float* wsf, int* wsi, int use_part) {
  const int b = blockIdx.x;
  const int t = threadIdx.x;
  float d2s, inst;
  if (use_part) {
    const float2* p = (const float2*)(wsf + OFF_PART + (((size_t)b * NCH) * Kk + t) * 2);
    d2s = 0.f; inst = 0.f;
    for (int ch = 0; ch < NCH; ++ch) {
      float2 v = p[(size_t)ch * Kk];
      d2s += v.x; inst += v.y;
    }
  } else {
    d2s = wsf[OFF_D2F + b * Kk + t];
    inst = (float)wsi[OFF_INSTF + b * Kk + t];
  }
  const int cnt = wsi[OFF_CNT + b * Kk + t];
  const float sumf = wsf[OFF_SUMF + b * Kk + t];
  float attr_p = 0.f, w = 0.f, wf = 0.f;
  if (cnt > 0) {
    attr_p = d2s / fmaxf(inst, 1.f);
    w = inst;
    wf = inst * (sumf / fmaxf((float)cnt, 1.f));
  }
  for (int o = 32; o > 0; o >>= 1) {
    attr_p += __shfl_down(attr_p, o);
    w += __shfl_down(w, o);
    wf += __shfl_down(wf, o);
  }
  __shared__ float r3[3][4];
  if ((t & 63) == 0) { r3[0][t >> 6] = attr_p; r3[1][t >> 6] = w; r3[2][t >> 6] = wf; }
  __syncthreads();
  if (t == 0) {
    float at = r3[0][0] + r3[0][1] + r3[0][2] + r3[0][3];
    float sw = r3[1][0] + r3[1][1] + r3[1][2] + r3[1][3];
    float swf = r3[2][0] + r3[2][1] + r3[2][2] + r3[2][3];
    float pos_bce = swf / fmaxf(sw, 1.f);
    float* sc = wsf + OFF_SCAL + b * 32;
    const float ce0n = sc[0] - sc[11];
    const float rneg_s = sc[2] - sc[12];
    const float rpos = sc[1], ce0b = sc[3], ncp = sc[4], nbg = sc[5];
    const int mv = wsi[OFF_SCAL + b * 32 + 6];
    const float nncp = (float)Nn - ncp;
    const float neg_bce = nncp > 0.f ? ce0n / fmaxf(nncp, 1.f) : 0.f;
    const float pos_m = rpos / fmaxf(ncp, 1.f);
    const float neg_m = nncp > 0.f ? rneg_s / fmaxf(nncp, 1.f) : 0.f;
    const float bg_bce = nbg > 0.f ? ce0b / fmaxf(nbg, 1.f) : 0.f;
    sc[8] = W_BPOS * pos_bce + W_BNEG * neg_bce + W_BBG * bg_bce + W_MARG * (pos_m + neg_m);
    sc[10] = at;
    const float nvalid = (float)Nn - nbg;
    wsi[OFF_SCAL + b * 32 + 7] = (nvalid > 0.f && mv > 0) ? 1 : 0;
  }
}

__global__ __launch_bounds__(256) void k_rep(const float* __restrict__ embed,
                                             float* wsf, int* wsi) {
  const int b = blockIdx.y;
  const int t = threadIdx.x;
  __shared__ int sidx[MCAP];
  __shared__ float cemb[256 * CSTR];
  __shared__ float csq[256];
  __shared__ float red[4];
  const int mv = wsi[OFF_SCAL + b * 32 + 6];
  const int msel = mv < MSEL ? mv : MSEL;
  const int mload = mv < MCAP ? mv : MCAP;
  for (int i = t; i < MCAP; i += 256)
    sidx[i] = (i < mload) ? wsi[OFF_CPIDX + b * MCAP + i] : 0x7FFFFFFF;
  __syncthreads();
  if (mv > MSEL) {
    for (int ksz = 2; ksz <= MCAP; ksz <<= 1) {
      for (int j = ksz >> 1; j > 0; j >>= 1) {
        for (int e = t; e < MCAP; e += 256) {
          int ixj = e ^ j;
          if (ixj > e) {
            bool up = ((e & ksz) == 0);
            int x = sidx[e], y = sidx[ixj];
            if ((x > y) == up) { sidx[e] = y; sidx[ixj] = x; }
          }
        }
        __syncthreads();
      }
    }
  }
  const float* eb = embed + (size_t)b * Nn * Dd;
  const int row = blockIdx.x * 64 + (t & 63);
  const int cg = t >> 6;
  const bool rok = row < msel;
  float r[Dd];
  float rsq = 0.f;
  if (rok) {
    const float4* s = (const float4*)(eb + (size_t)sidx[row] * Dd);
    float4 v0 = s[0], v1 = s[1], v2 = s[2], v3 = s[3];
    r[0]=v0.x; r[1]=v0.y; r[2]=v0.z; r[3]=v0.w;
    r[4]=v1.x; r[5]=v1.y; r[6]=v1.z; r[7]=v1.w;
    r[8]=v2.x; r[9]=v2.y; r[10]=v2.z; r[11]=v2.w;
    r[12]=v3.x; r[13]=v3.y; r[14]=v3.z; r[15]=v3.w;
    #pragma unroll
    for (int d = 0; d < Dd; ++d) rsq += r[d] * r[d];
  }
  float acc = 0.f;
  for (int c0 = 0; c0 < msel; c0 += 256) {
    const int nc = (msel - c0) < 256 ? (msel - c0) : 256;
    __syncthreads();
    for (int wvi = t; wvi < nc * 4; wvi += 256) {
      int col = wvi >> 2, q = wvi & 3;
      float4 v = ((const float4*)(eb + (size_t)sidx[c0 + col] * Dd))[q];
      *(float4*)&cemb[col * CSTR + q * 4] = v;
    }
    __syncthreads();
    for (int col = t; col < nc; col += 256) {
      float s = 0.f;
      #pragma unroll
      for (int d = 0; d < Dd; ++d) s += cemb[col * CSTR + d] * cemb[col * CSTR + d];
      csq[col] = s;
    }
    __syncthreads();
    if (rok) {
      for (int c = cg; c < nc; c += 4) {
        float dotrc = 0.f;
        #pragma unroll
        for (int d = 0; d < Dd; ++d) dotrc += r[d] * cemb[c * CSTR + d];
        acc += __expf(2.f * dotrc - rsq - csq[c]);
      }
    }
  }
  for (int o = 32; o > 0; o >>= 1) acc += __shfl_down(acc, o);
  if ((t & 63) == 0) red[t >> 6] = acc;
  __syncthreads();
  if (t == 0) {
    float s = red[0] + red[1] + red[2] + red[3];
    if (s != 0.f) atomicAdd(&wsf[OFF_SCAL + b * 32 + 9], s);
  }
}

__global__ void k_final(float* wsf, int* wsi, float* out, int out_size) {
  const int t = threadIdx.x;
  if (t == 0) {
    float total = 0.f;
    int cnt = 0;
    for (int b = 0; b < Bn; ++b) {
      float* sc = wsf + OFF_SCAL + b * 32;
      int* sci = wsi + OFF_SCAL + b * 32;
      int mv = sci[6];
      if (sci[7]) {
        float mvf = (float)mv;
        float rep = (mv > 1) ? W_REP * sc[9] / fmaxf(mvf * mvf, 1.f) : 0.f;
        total += sc[8] + W_ATTR * sc[10] + rep;
        cnt++;
      }
    }
    out[0] = (cnt > 0) ? total / (float)cnt : 0.f;
  }
  for (int i = 1 + t; i < out_size; i += 256) out[i] = 0.f;
}

extern "C" void kernel_launch(void* const* d_in, const int* in_sizes, int n_in,
                              void* d_out, int out_size, void* d_ws, size_t ws_size,
                              hipStream_t stream) {
  const float* beta = (const float*)d_in[0];
  const float* embed = (const float*)d_in[1];
  const int* sid = (const int*)d_in[2];
  const void* cp = d_in[3];
  float* out = (float*)d_out;
  float* wsf = (float*)d_ws;
  int* wsi = (int*)d_ws;
  const int use_part = ws_size >= WS_NEEDED ? 1 : 0;

  hipMemsetAsync(d_ws, 0, (size_t)ZERO_WORDS * 4, stream);
  k_detect<<<256, 256, 0, stream>>>((const uint4*)cp, wsi);
  k_cplist<<<2048, 256, 0, stream>>>(beta, sid, cp, wsf, wsi);
  k_anchor<<<Bn, 256, 0, stream>>>(embed, wsf, wsi);
  dim3 gp(NCH, Bn);
  k_pass<<<gp, 256, 0, stream>>>(beta, sid, embed, wsf, wsi, use_part);
  k_redev<<<Bn, 256, 0, stream>>>(wsf, wsi, use_part);
  dim3 gr(MSEL / 64, Bn);
  k_rep<<<gr, 256, 0, stream>>>(embed, wsf, wsi);
  k_final<<<1, 256, 0, stream>>>(wsf, wsi, out, out_size);
}